// Round 1
// baseline (20999.599 us; speedup 1.0000x reference)
//
#include <hip/hip_runtime.h>

#define BSZ 2048
#define SEQ 50
#define HID 128
#define NHEAD 4
#define HDIM 32
#define INNER 512
#define NITEMS 50000
#define NOUT 49999
#define LROWS 32

__global__ void embed_k(const int* __restrict__ ids, const float* __restrict__ emb,
                        const float* __restrict__ pos, float* __restrict__ x){
  int row = blockIdx.x;          // b*SEQ + l
  int l = row % SEQ;
  int t = threadIdx.x;
  int id = ids[row];
  x[(size_t)row*HID + t] = emb[(size_t)id*HID + t] + pos[l*HID + t];
}

// x_in/x_out bmm with A, concat, @ mixW.T + mixb  (one block per (b,l) row)
__global__ void mix_k(const float* __restrict__ A, const float* __restrict__ xin_,
                      const float* __restrict__ mixW, const float* __restrict__ mixb,
                      float* __restrict__ xout_){
  int row = blockIdx.x; int b = row / SEQ; int t = threadIdx.x;
  __shared__ float Ar[100];
  __shared__ __align__(16) float cat[256];
  if (t < 100) Ar[t] = A[(size_t)row*100 + t];
  __syncthreads();
  float xi = 0.f, xo = 0.f;
  const float* xb = xin_ + (size_t)b*SEQ*HID;
  #pragma unroll 5
  for (int m = 0; m < SEQ; ++m){
    float v = xb[m*HID + t];
    xi += Ar[m]*v;
    xo += Ar[50+m]*v;
  }
  cat[t] = xi; cat[128+t] = xo;
  __syncthreads();
  float acc = mixb[t];
  const float4* w = (const float4*)(mixW + (size_t)t*256);
  const float4* c4 = (const float4*)cat;
  #pragma unroll 8
  for (int j = 0; j < 64; ++j){
    float4 wv = w[j]; float4 cv = c4[j];
    acc += wv.x*cv.x + wv.y*cv.y + wv.z*cv.z + wv.w*cv.w;
  }
  xout_[(size_t)row*HID + t] = acc;
}

// fused qkv + scores + softmax + PV, one block per (b, head)
__global__ void attn_k(const float* __restrict__ x, const float* __restrict__ Wq,
                       const float* __restrict__ bq, const float* __restrict__ Wk,
                       const float* __restrict__ bk, const float* __restrict__ Wv,
                       const float* __restrict__ bv, float* __restrict__ o){
  int blk = blockIdx.x; int b = blk / NHEAD; int h = blk % NHEAD;
  int t = threadIdx.x;
  __shared__ float qs[SEQ][HDIM];
  __shared__ float ks[SEQ][HDIM];
  __shared__ float vs[SEQ][HDIM];
  __shared__ float ss[SEQ][SEQ+2];
  const float* xb = x + (size_t)b*SEQ*HID;
  for (int task = t; task < SEQ*HDIM; task += 256){
    int l = task >> 5, d = task & 31;
    int r = h*HDIM + d;
    const float* xr = xb + l*HID;
    const float* wq = Wq + r*HID;
    const float* wk = Wk + r*HID;
    const float* wv = Wv + r*HID;
    float aq = bq[r], ak = bk[r], av = bv[r];
    #pragma unroll 8
    for (int c = 0; c < HID; ++c){
      float xv = xr[c];
      aq += xv*wq[c]; ak += xv*wk[c]; av += xv*wv[c];
    }
    qs[l][d]=aq; ks[l][d]=ak; vs[l][d]=av;
  }
  __syncthreads();
  for (int task = t; task < SEQ*SEQ; task += 256){
    int l = task / SEQ, m = task % SEQ;
    float a = 0.f;
    #pragma unroll
    for (int d = 0; d < HDIM; ++d) a += qs[l][d]*ks[m][d];
    ss[l][m] = a * 0.17677669529663687f;  // 1/sqrt(32)
  }
  __syncthreads();
  if (t < SEQ){
    float mx = -1e30f;
    for (int m = 0; m < SEQ; ++m) mx = fmaxf(mx, ss[t][m]);
    float sum = 0.f;
    for (int m = 0; m < SEQ; ++m){ float e = __expf(ss[t][m]-mx); ss[t][m]=e; sum+=e; }
    float inv = 1.f/sum;
    for (int m = 0; m < SEQ; ++m) ss[t][m] *= inv;
  }
  __syncthreads();
  for (int task = t; task < SEQ*HDIM; task += 256){
    int l = task >> 5, d = task & 31;
    float a = 0.f;
    for (int m = 0; m < SEQ; ++m) a += ss[l][m]*vs[m][d];
    o[((size_t)b*SEQ+l)*HID + h*HDIM + d] = a;
  }
}

// o @ Wo.T + bo + residual, then LayerNorm. One block (128 thr) per row.
__global__ void oproj_ln_k(const float* __restrict__ o, const float* __restrict__ Wo,
                           const float* __restrict__ bo, const float* __restrict__ g,
                           const float* __restrict__ be, float* __restrict__ x){
  int row = blockIdx.x; int t = threadIdx.x;
  __shared__ __align__(16) float orow[HID];
  __shared__ float red[HID];
  orow[t] = o[(size_t)row*HID + t];
  __syncthreads();
  float acc = bo[t];
  const float4* w = (const float4*)(Wo + (size_t)t*HID);
  const float4* c4 = (const float4*)orow;
  #pragma unroll 8
  for (int j = 0; j < 32; ++j){
    float4 wv = w[j]; float4 cv = c4[j];
    acc += wv.x*cv.x + wv.y*cv.y + wv.z*cv.z + wv.w*cv.w;
  }
  float val = x[(size_t)row*HID + t] + acc;
  red[t] = val; __syncthreads();
  for (int s = 64; s > 0; s >>= 1){ if (t < s) red[t] += red[t+s]; __syncthreads(); }
  float mean = red[0] * (1.f/HID);
  __syncthreads();
  float dv = val - mean;
  red[t] = dv*dv; __syncthreads();
  for (int s = 64; s > 0; s >>= 1){ if (t < s) red[t] += red[t+s]; __syncthreads(); }
  float var = red[0] * (1.f/HID);
  float r = rsqrtf(var + 1e-5f);
  x[(size_t)row*HID + t] = dv * r * g[t] + be[t];
}

// relu(x@W1.T+b1)@W2.T+b2 + residual, then LayerNorm. One block (256 thr) per row.
__global__ void ffn_ln_k(const float* __restrict__ W1, const float* __restrict__ b1,
                         const float* __restrict__ W2, const float* __restrict__ b2,
                         const float* __restrict__ g, const float* __restrict__ be,
                         float* __restrict__ x){
  int row = blockIdx.x; int t = threadIdx.x;
  __shared__ __align__(16) float xr[HID];
  __shared__ __align__(16) float hs[INNER];
  __shared__ float red[HID];
  if (t < HID) xr[t] = x[(size_t)row*HID + t];
  __syncthreads();
  for (int j = t; j < INNER; j += 256){
    float acc = b1[j];
    const float4* w = (const float4*)(W1 + (size_t)j*HID);
    const float4* c4 = (const float4*)xr;
    #pragma unroll 8
    for (int q = 0; q < 32; ++q){
      float4 wv=w[q]; float4 cv=c4[q];
      acc += wv.x*cv.x + wv.y*cv.y + wv.z*cv.z + wv.w*cv.w;
    }
    hs[j] = fmaxf(acc, 0.f);
  }
  __syncthreads();
  float val = 0.f;
  if (t < HID){
    float acc = b2[t];
    const float4* w = (const float4*)(W2 + (size_t)t*INNER);
    const float4* c4 = (const float4*)hs;
    #pragma unroll 8
    for (int q = 0; q < 128; ++q){
      float4 wv=w[q]; float4 cv=c4[q];
      acc += wv.x*cv.x + wv.y*cv.y + wv.z*cv.z + wv.w*cv.w;
    }
    val = xr[t] + acc;
    red[t] = val;
  }
  __syncthreads();
  for (int s = 64; s > 0; s >>= 1){ if (t < s) red[t] += red[t+s]; __syncthreads(); }
  float mean = red[0] * (1.f/HID);
  __syncthreads();
  float dv = val - mean;
  if (t < HID) red[t] = dv*dv;
  __syncthreads();
  for (int s = 64; s > 0; s >>= 1){ if (t < s) red[t] += red[t+s]; __syncthreads(); }
  if (t < HID){
    float var = red[0] * (1.f/HID);
    float r = rsqrtf(var + 1e-5f);
    x[(size_t)row*HID + t] = dv * r * g[t] + be[t];
  }
}

// attention pooling + session vector. One block (128 thr) per batch elem.
__global__ void final_k(const float* __restrict__ x, const float* __restrict__ attW,
                        const float* __restrict__ attb, const float* __restrict__ sessW,
                        const float* __restrict__ sessb, float* __restrict__ sess){
  int b = blockIdx.x; int t = threadIdx.x;
  __shared__ float av[SEQ];
  __shared__ __align__(16) float cat[256];
  const float* xb = x + (size_t)b*SEQ*HID;
  if (t < SEQ){
    float a = attb[0];
    for (int c = 0; c < HID; ++c) a += xb[t*HID + c]*attW[c];
    av[t] = a;
  }
  __syncthreads();
  if (t == 0){
    float s = 0.f;
    for (int l = 0; l < SEQ; ++l) s += av[l];
    float inv = 1.f/s;
    for (int l = 0; l < SEQ; ++l) av[l] *= inv;
  }
  __syncthreads();
  float gacc = 0.f;
  for (int l = 0; l < SEQ; ++l) gacc += xb[l*HID + t]*av[l];
  cat[t] = xb[49*HID + t];
  cat[128+t] = gacc;
  __syncthreads();
  float acc = sessb[t];
  const float4* w = (const float4*)(sessW + (size_t)t*256);
  const float4* c4 = (const float4*)cat;
  #pragma unroll 8
  for (int j = 0; j < 64; ++j){
    float4 wv=w[j]; float4 cv=c4[j];
    acc += wv.x*cv.x + wv.y*cv.y + wv.z*cv.z + wv.w*cv.w;
  }
  sess[(size_t)b*HID + t] = acc;
}

// logits = sess @ emb[1:].T   (2048 x 49999, K=128)
__global__ void logits_k(const float* __restrict__ sess, const float* __restrict__ emb,
                         float* __restrict__ out){
  int t = threadIdx.x;
  int n0 = blockIdx.x * 256;
  int r0 = blockIdx.y * LROWS;
  __shared__ __align__(16) float ss[LROWS][HID];
  float* ssf = (float*)ss;
  for (int i = t; i < LROWS*HID; i += 256) ssf[i] = sess[(size_t)r0*HID + i];
  __syncthreads();
  int n = n0 + t;
  if (n >= NOUT) return;
  const float4* er = (const float4*)(emb + (size_t)(1+n)*HID);
  float acc[LROWS];
  #pragma unroll
  for (int r = 0; r < LROWS; ++r) acc[r] = 0.f;
  for (int c4i = 0; c4i < 32; ++c4i){
    float4 e = er[c4i];
    int c = c4i*4;
    #pragma unroll
    for (int r = 0; r < LROWS; ++r){
      acc[r] += e.x*ss[r][c] + e.y*ss[r][c+1] + e.z*ss[r][c+2] + e.w*ss[r][c+3];
    }
  }
  #pragma unroll
  for (int r = 0; r < LROWS; ++r){
    out[(size_t)(r0+r)*NOUT + n] = acc[r];
  }
}

extern "C" void kernel_launch(void* const* d_in, const int* in_sizes, int n_in,
                              void* d_out, int out_size, void* d_ws, size_t ws_size,
                              hipStream_t stream){
  const int*   ids  = (const int*)d_in[0];
  const float* A    = (const float*)d_in[1];
  const float* emb  = (const float*)d_in[2];
  const float* pos  = (const float*)d_in[3];
  const float* mixW = (const float*)d_in[4];
  const float* mixb = (const float*)d_in[5];
  const float* Wq   = (const float*)d_in[6];
  const float* bq   = (const float*)d_in[7];
  const float* Wk   = (const float*)d_in[8];
  const float* bk   = (const float*)d_in[9];
  const float* Wv   = (const float*)d_in[10];
  const float* bv   = (const float*)d_in[11];
  const float* Wo   = (const float*)d_in[12];
  const float* bo   = (const float*)d_in[13];
  const float* ln1g = (const float*)d_in[14];
  const float* ln1b = (const float*)d_in[15];
  const float* W1   = (const float*)d_in[16];
  const float* b1   = (const float*)d_in[17];
  const float* W2   = (const float*)d_in[18];
  const float* b2   = (const float*)d_in[19];
  const float* ln2g = (const float*)d_in[20];
  const float* ln2b = (const float*)d_in[21];
  const float* attW = (const float*)d_in[22];
  const float* attb = (const float*)d_in[23];
  const float* sessW= (const float*)d_in[24];
  const float* sessb= (const float*)d_in[25];
  float* out = (float*)d_out;

  float* xA   = (float*)d_ws;
  float* xB   = xA + (size_t)BSZ*SEQ*HID;
  float* sess = xB + (size_t)BSZ*SEQ*HID;

  embed_k<<<BSZ*SEQ, HID, 0, stream>>>(ids, emb, pos, xA);
  float* xc = xA; float* xn = xB;
  for (int i = 0; i < 2; ++i){
    mix_k<<<BSZ*SEQ, HID, 0, stream>>>(A, xc, mixW + (size_t)i*HID*2*HID, mixb + i*HID, xn);
    attn_k<<<BSZ*NHEAD, 256, 0, stream>>>(xn, Wq + (size_t)i*HID*HID, bq + i*HID,
                                          Wk + (size_t)i*HID*HID, bk + i*HID,
                                          Wv + (size_t)i*HID*HID, bv + i*HID, xc);
    oproj_ln_k<<<BSZ*SEQ, HID, 0, stream>>>(xc, Wo + (size_t)i*HID*HID, bo + i*HID,
                                            ln1g + i*HID, ln1b + i*HID, xn);
    ffn_ln_k<<<BSZ*SEQ, 256, 0, stream>>>(W1 + (size_t)i*INNER*HID, b1 + i*INNER,
                                          W2 + (size_t)i*HID*INNER, b2 + i*HID,
                                          ln2g + i*HID, ln2b + i*HID, xn);
    float* tmp = xc; xc = xn; xn = tmp;
  }
  final_k<<<BSZ, HID, 0, stream>>>(xc, attW, attb, sessW, sessb, sess);
  dim3 lgrid((NOUT + 255)/256, BSZ/LROWS);
  logits_k<<<lgrid, 256, 0, stream>>>(sess, emb, out);
}